// Round 14
// baseline (145.787 us; speedup 1.0000x reference)
//
#include <hip/hip_runtime.h>

#define B_ 4
#define T_ 4096
#define C_ 1024
#define H_ 64

typedef _Float16 half8  __attribute__((ext_vector_type(8)));
typedef _Float16 half4_ __attribute__((ext_vector_type(4)));
typedef float    floatx4 __attribute__((ext_vector_type(4)));

#define MFMA16(a, b, c)  __builtin_amdgcn_mfma_f32_16x16x32_f16(a, b, c, 0, 0, 0)
#define MFMA16K(a, b, c) __builtin_amdgcn_mfma_f32_16x16x16f16(a, b, c, 0, 0, 0)
#define LO4(v) __builtin_shufflevector(v, v, 0, 1, 2, 3)
#define HI4(v) __builtin_shufflevector(v, v, 4, 5, 6, 7)

// ---------------------------------------------------------------------------
// Kernel 1: pack W into MFMA-fragment order (96 blocks, half8 stores).
// ---------------------------------------------------------------------------
__global__ __launch_bounds__(256) void pack_w_kn(
    const float* __restrict__ Wq, const float* __restrict__ Wk,
    const float* __restrict__ Wv, _Float16* __restrict__ Wt2)
{
    const int base = (blockIdx.x * 256 + threadIdx.x) * 8;  // 0..196600, step 8
    const int mt   = base >> 14;
    const int j    = (base >> 10) & 15;
    const int f    = (base >> 9) & 1;
    const int lane = (base >> 3) & 63;
    const int q = lane >> 4, c = lane & 15;
    const int k0 = j * 64 + f * 32 + q * 8;
    const int hp = mt * 16 + c;                       // 0..191
    const float* W = (hp < 64) ? Wq : (hp < 128) ? Wk : Wv;
    const float* src = W + k0 * H_ + (hp & 63);
    half8 v;
    #pragma unroll
    for (int jj = 0; jj < 8; ++jj) v[jj] = (_Float16)src[jj * H_];
    *(half8*)(Wt2 + base) = v;
}

// ---------------------------------------------------------------------------
// Kernel 2: fused QKV projection (unchanged; at its 92 MB memory roofline).
// ---------------------------------------------------------------------------
__global__ __launch_bounds__(512) void qkv_kn(
    const float* __restrict__ x, const _Float16* __restrict__ Wt2,
    _Float16* __restrict__ Qh, _Float16* __restrict__ Kpk,
    _Float16* __restrict__ Vpk)
{
    __shared__ _Float16 xs[2][32][72];                // 9216 B
    const int tid  = threadIdx.x;
    const int lane = tid & 63, w = tid >> 6;
    const int q    = lane >> 4, c = lane & 15;
    const int nt   = w & 1;                           // n-half (16 rows)
    const int mg   = w >> 1;                          // m-group (3 m-tiles)
    const int row0 = blockIdx.x * 32;

    const int srow = tid >> 4, scol = (tid & 15) * 4;
    const float* xg = x + (size_t)(row0 + srow) * C_ + scol;

    floatx4 acc[3];
    #pragma unroll
    for (int i = 0; i < 3; ++i) acc[i] = floatx4{0.f, 0.f, 0.f, 0.f};

    float4 g = *(const float4*)xg;                    // preload tile 0

    for (int j = 0; j < 16; ++j) {
        half4_ hv;
        hv[0] = (_Float16)g.x; hv[1] = (_Float16)g.y;
        hv[2] = (_Float16)g.z; hv[3] = (_Float16)g.w;
        *(half4_*)(&xs[j & 1][srow][scol]) = hv;
        __syncthreads();
        if (j < 15) g = *(const float4*)(xg + (j + 1) * 64);

        const _Float16* xrow = &xs[j & 1][nt * 16 + c][q * 8];
        const half8 b0 = *(const half8*)xrow;
        const half8 b1 = *(const half8*)(xrow + 32);

        half8 a[6];
        #pragma unroll
        for (int i = 0; i < 3; ++i) {
            const size_t fb = ((size_t)((mg * 3 + i) * 16 + j) * 2) * 512 + lane * 8;
            a[i * 2]     = *(const half8*)(Wt2 + fb);
            a[i * 2 + 1] = *(const half8*)(Wt2 + fb + 512);
        }
        #pragma unroll
        for (int i = 0; i < 3; ++i) {
            acc[i] = MFMA16(a[i * 2],     b0, acc[i]);
            acc[i] = MFMA16(a[i * 2 + 1], b1, acc[i]);
        }
    }

    const int row = row0 + nt * 16 + c;
    const int b = row >> 12, t4 = row & (T_ - 1);
    const int kt = t4 >> 6;
    const size_t tbase = ((size_t)b * 64 + kt) * 4096;
    const int mtk = (t4 >> 4) & 3;
    const int kk  = t4 & 63;

    #pragma unroll
    for (int i = 0; i < 3; ++i) {
        const int gi = mg * 3 + i;
        if (gi < 4) {                                 // Q row-major
            half4_ v;
            #pragma unroll
            for (int r = 0; r < 4; ++r) v[r] = (_Float16)acc[i][r];
            *(half4_*)(Qh + (size_t)row * H_ + gi * 16 + q * 4) = v;
        } else if (gi < 8) {                          // K fragment-packed (16x16x32 A-frag)
            half4_ v;
            #pragma unroll
            for (int r = 0; r < 4; ++r) v[r] = (_Float16)acc[i][r];
            const int e  = gi - 4;
            const int f  = e >> 1;
            const int qa = (e * 2 + (q >> 1)) & 3;
            *(half4_*)(Kpk + tbase + ((size_t)(mtk * 2 + f) * 64 + qa * 16 + c) * 8
                       + (q & 1) * 4) = v;
        } else {                                      // V 16x16x16 A-frag packed
            const int mtv = gi - 8;
            const int qa2 = (kk >> 2) & 3;
            const int h4  = (kk >> 4) & 1;
            const int f2  = kk >> 5;
            const int i2  = kk & 3;
            #pragma unroll
            for (int r = 0; r < 4; ++r) {
                const int cv = q * 4 + r;             // h & 15
                Vpk[tbase + ((size_t)(mtv * 2 + f2) * 64 + qa2 * 16 + cv) * 8
                    + h4 * 4 + i2] = (_Float16)acc[i][r];
            }
        }
    }
}

// ---------------------------------------------------------------------------
// Kernel 3: causal flash attention, QBLK=32 at __launch_bounds__(256, 3) —
// the one untested cell of the traffic/register matrix: 170-VGPR budget fits
// QBLK=32's ~140-reg live set (the r5-r7 spill was the 128 budget of
// (512,4)), halving K/V traffic 467 -> 266 MB with NO global partials and NO
// split-K plumbing.  Block = 4 waves, each wave owns the SAME 32 q-rows
// (2x16 groups), in-block 4-way split-K over kt; combine across the 4 waves
// is pure-LDS (r2's proven 2-pass form).  Guarded K-prefetch, V-after-QK,
// T13 defer-rescale, setprio, balanced heavy+light fold, batch per XCD pair.
// ---------------------------------------------------------------------------
__global__ __launch_bounds__(256, 3) void attn_kn(
    const _Float16* __restrict__ Qh, const _Float16* __restrict__ Kpk,
    const _Float16* __restrict__ Vpk, float* __restrict__ out)
{
    __shared__ __align__(16) char smem[18432];        // Ol[4][1088] + Ml + Ll
    const int tid  = threadIdx.x;
    const int lane = tid & 63;
    const int w    = tid >> 6;                        // 0..3
    const int q    = lane >> 4, c = lane & 15;

    // decode: batch per XCD pair; balanced heavy+light fold over 512 blocks
    const int bid  = blockIdx.x;
    const int xcd  = bid & 7;
    const int slot = bid >> 3;                        // 0..63
    const int b    = xcd >> 1;
    const int e    = xcd & 1;
    const int t32  = (slot < 32) ? (127 - (2 * slot + e))
                                 : (2 * (slot - 32) + e);
    const int row0 = t32 * 32;
    const int grow = b * T_ + row0;
    const int nk   = (t32 >> 1) + 1;                  // same for both groups

    // Q B-frags for the two 16-row groups, pre-scaled by (1/8)*log2(e)
    const _Float16 qs = (_Float16)0.18033688f;
    half8 bq0[2], bq1[2];
    #pragma unroll
    for (int g = 0; g < 2; ++g) {
        const _Float16* qb = Qh + (size_t)(grow + g * 16 + c) * H_;
        bq0[g] = *(const half8*)(qb + q * 8);
        bq1[g] = *(const half8*)(qb + 32 + q * 8);
        bq0[g] *= qs; bq1[g] *= qs;
    }

    floatx4 o[4][2];
    #pragma unroll
    for (int i = 0; i < 4; ++i)
        #pragma unroll
        for (int g = 0; g < 2; ++g) o[i][g] = floatx4{0.f, 0.f, 0.f, 0.f};
    float m[2] = {-3.0e38f, -3.0e38f}, l[2] = {0.f, 0.f};

    const _Float16* Kb = Kpk + (size_t)b * 262144;    // b * 64 * 4096
    const _Float16* Vb = Vpk + (size_t)b * 262144;

    half8 k0[4], k1[4], v0[4], v1[4];
    {   // preload K for this wave's first tile (kt = w; index <= 3 < 64)
        const _Float16* Kt = Kb + (size_t)w * 4096;
        #pragma unroll
        for (int mt = 0; mt < 4; ++mt) {
            k0[mt] = *(const half8*)(Kt + ((mt * 2)     * 64 + lane) * 8);
            k1[mt] = *(const half8*)(Kt + ((mt * 2 + 1) * 64 + lane) * 8);
        }
    }

    #pragma unroll 1
    for (int kt = w; kt < nk; kt += 4) {
        const int kb = kt * 64;

        // QK^T: 64 keys x 32 q (2 groups)
        floatx4 s[4][2];
        __builtin_amdgcn_s_setprio(1);
        #pragma unroll
        for (int mt = 0; mt < 4; ++mt)
            #pragma unroll
            for (int g = 0; g < 2; ++g) {
                floatx4 z = floatx4{0.f, 0.f, 0.f, 0.f};
                z = MFMA16(k0[mt], bq0[g], z);
                s[mt][g] = MFMA16(k1[mt], bq1[g], z);
            }
        __builtin_amdgcn_s_setprio(0);

        // V(kt): latency hides under softmax
        const _Float16* Vt = Vb + (size_t)kt * 4096;
        #pragma unroll
        for (int mt = 0; mt < 4; ++mt) {
            v0[mt] = *(const half8*)(Vt + ((mt * 2)     * 64 + lane) * 8);
            v1[mt] = *(const half8*)(Vt + ((mt * 2 + 1) * 64 + lane) * 8);
        }
        // K(kt+4) prefetch into the just-freed K regs (guarded, wave-uniform)
        if (kt + 4 < nk) {
            const _Float16* Kt = Kb + (size_t)(kt + 4) * 4096;
            #pragma unroll
            for (int mt = 0; mt < 4; ++mt) {
                k0[mt] = *(const half8*)(Kt + ((mt * 2)     * 64 + lane) * 8);
                k1[mt] = *(const half8*)(Kt + ((mt * 2 + 1) * 64 + lane) * 8);
            }
        }

        if (kt == nk - 1) {                           // causal mask (diag tile)
            #pragma unroll
            for (int mt = 0; mt < 4; ++mt)
                #pragma unroll
                for (int g = 0; g < 2; ++g)
                    #pragma unroll
                    for (int r = 0; r < 4; ++r)
                        if (kb + mt * 16 + q * 4 + r > row0 + g * 16 + c)
                            s[mt][g][r] = -3.0e38f;
        }

        // online softmax per group; lane holds 16 scores of ONE q-row
        half4_ ph[2][4];
        #pragma unroll
        for (int g = 0; g < 2; ++g) {
            float mx = s[0][g][0];
            #pragma unroll
            for (int mt = 0; mt < 4; ++mt)
                #pragma unroll
                for (int r = 0; r < 4; ++r) mx = fmaxf(mx, s[mt][g][r]);
            mx = fmaxf(mx, __shfl_xor(mx, 16, 64));
            mx = fmaxf(mx, __shfl_xor(mx, 32, 64));
            if (!__all(mx <= m[g] + 8.f)) {           // T13 defer-rescale
                const float mn    = fmaxf(m[g], mx);
                const float alpha = exp2f(m[g] - mn);
                l[g] *= alpha;
                #pragma unroll
                for (int mt = 0; mt < 4; ++mt) o[mt][g] *= alpha;
                m[g] = mn;
            }
            float sl = 0.f;
            #pragma unroll
            for (int mt = 0; mt < 4; ++mt)
                #pragma unroll
                for (int r = 0; r < 4; ++r) {
                    const float ev = exp2f(s[mt][g][r] - m[g]);
                    sl += ev;
                    ph[g][mt][r] = (_Float16)ev;
                }
            sl += __shfl_xor(sl, 16, 64);
            sl += __shfl_xor(sl, 32, 64);
            l[g] += sl;
        }

        // O^T += V^T · P^T (P in registers as 16x16x16 B-frags)
        __builtin_amdgcn_s_setprio(1);
        #pragma unroll
        for (int mt = 0; mt < 4; ++mt) {
            const half4_ va = LO4(v0[mt]);
            const half4_ vb = HI4(v0[mt]);
            const half4_ vc = LO4(v1[mt]);
            const half4_ vd = HI4(v1[mt]);
            #pragma unroll
            for (int g = 0; g < 2; ++g) {
                o[mt][g] = MFMA16K(va, ph[g][0], o[mt][g]);
                o[mt][g] = MFMA16K(vb, ph[g][1], o[mt][g]);
                o[mt][g] = MFMA16K(vc, ph[g][2], o[mt][g]);
                o[mt][g] = MFMA16K(vd, ph[g][3], o[mt][g]);
            }
        }
        __builtin_amdgcn_s_setprio(0);
    }

    // ---- flash combine across the 4 waves: 2 passes over groups ----------
    float* Ol = (float*)smem;                         // [4][1088] (pad 17)
    float* Ml = (float*)(smem + 17408);               // [4][32]
    float* Ll = (float*)(smem + 17920);               // [4][32]
    if (q == 0) { Ml[w * 32 + c] = m[0]; Ml[w * 32 + 16 + c] = m[1]; }
    __syncthreads();
    float M0 = Ml[c], M1 = Ml[16 + c];
    #pragma unroll
    for (int w2 = 1; w2 < 4; ++w2) {
        M0 = fmaxf(M0, Ml[w2 * 32 + c]);
        M1 = fmaxf(M1, Ml[w2 * 32 + 16 + c]);
    }
    const float alpha0 = exp2f(m[0] - M0);            // 0 for empty waves
    const float alpha1 = exp2f(m[1] - M1);
    if (q == 0) { Ll[w * 32 + c] = l[0] * alpha0; Ll[w * 32 + 16 + c] = l[1] * alpha1; }

    const int c2 = tid >> 4;                          // output q-row 0..15
    const int h0 = (tid & 15) * 4;                    // h segment
    #pragma unroll
    for (int gp = 0; gp < 2; ++gp) {
        const float a = gp ? alpha1 : alpha0;
        #pragma unroll
        for (int mt = 0; mt < 4; ++mt)
            #pragma unroll
            for (int r = 0; r < 4; ++r)
                Ol[w * 1088 + (mt * 16 + q * 4 + r) * 17 + c] = o[mt][gp][r] * a;
        __syncthreads();
        float L = 0.f;
        #pragma unroll
        for (int w2 = 0; w2 < 4; ++w2) L += Ll[w2 * 32 + gp * 16 + c2];
        const float inv = 1.f / L;
        floatx4 st = floatx4{0.f, 0.f, 0.f, 0.f};
        #pragma unroll
        for (int w2 = 0; w2 < 4; ++w2)
            #pragma unroll
            for (int r = 0; r < 4; ++r)
                st[r] += Ol[w2 * 1088 + (h0 + r) * 17 + c2];
        st *= inv;
        *(floatx4*)(out + (size_t)(grow + gp * 16 + c2) * H_ + h0) = st;
        __syncthreads();                              // before pass-1 overwrite
    }
}

extern "C" void kernel_launch(void* const* d_in, const int* in_sizes, int n_in,
                              void* d_out, int out_size, void* d_ws, size_t ws_size,
                              hipStream_t stream) {
    const float* x  = (const float*)d_in[0];
    const float* Wq = (const float*)d_in[1];
    const float* Wk = (const float*)d_in[2];
    const float* Wv = (const float*)d_in[3];
    float* out = (float*)d_out;

    _Float16* ws = (_Float16*)d_ws;
    _Float16* Wt2 = ws;                               //   192*1024 = 196608
    _Float16* Qh  = ws + 196608;                      // 16384*64  = 1048576
    _Float16* Kpk = Qh + 1048576;                     // [4][64][4096]
    _Float16* Vpk = Kpk + 1048576;                    // [4][64][4096]

    hipLaunchKernelGGL(pack_w_kn, dim3(96), dim3(256), 0, stream, Wq, Wk, Wv, Wt2);
    hipLaunchKernelGGL(qkv_kn, dim3((B_ * T_) / 32), dim3(512), 0, stream,
                       x, Wt2, Qh, Kpk, Vpk);
    hipLaunchKernelGGL(attn_kn, dim3(512), dim3(256), 0, stream,
                       Qh, Kpk, Vpk, out);
}

// Round 15
// 139.170 us; speedup vs baseline: 1.0475x; 1.0475x over previous
//
#include <hip/hip_runtime.h>

#define B_ 4
#define T_ 4096
#define C_ 1024
#define H_ 64

typedef _Float16 half8  __attribute__((ext_vector_type(8)));
typedef _Float16 half4_ __attribute__((ext_vector_type(4)));
typedef float    floatx4 __attribute__((ext_vector_type(4)));

#define MFMA16(a, b, c)  __builtin_amdgcn_mfma_f32_16x16x32_f16(a, b, c, 0, 0, 0)
#define MFMA16K(a, b, c) __builtin_amdgcn_mfma_f32_16x16x16f16(a, b, c, 0, 0, 0)
#define LO4(v) __builtin_shufflevector(v, v, 0, 1, 2, 3)
#define HI4(v) __builtin_shufflevector(v, v, 4, 5, 6, 7)

// ---------------------------------------------------------------------------
// Kernel 1: pack W into MFMA-fragment order (96 blocks, half8 stores).
// ---------------------------------------------------------------------------
__global__ __launch_bounds__(256) void pack_w_kn(
    const float* __restrict__ Wq, const float* __restrict__ Wk,
    const float* __restrict__ Wv, _Float16* __restrict__ Wt2)
{
    const int base = (blockIdx.x * 256 + threadIdx.x) * 8;  // 0..196600, step 8
    const int mt   = base >> 14;
    const int j    = (base >> 10) & 15;
    const int f    = (base >> 9) & 1;
    const int lane = (base >> 3) & 63;
    const int q = lane >> 4, c = lane & 15;
    const int k0 = j * 64 + f * 32 + q * 8;
    const int hp = mt * 16 + c;                       // 0..191
    const float* W = (hp < 64) ? Wq : (hp < 128) ? Wk : Wv;
    const float* src = W + k0 * H_ + (hp & 63);
    half8 v;
    #pragma unroll
    for (int jj = 0; jj < 8; ++jj) v[jj] = (_Float16)src[jj * H_];
    *(half8*)(Wt2 + base) = v;
}

// ---------------------------------------------------------------------------
// Kernel 2: fused QKV projection (at its 92 MB memory roofline, ~14.6 us).
// Vpk written in 16x16x16 A-frag order so attn's PV consumes the QK^T
// C-fragment directly from registers.
// ---------------------------------------------------------------------------
__global__ __launch_bounds__(512) void qkv_kn(
    const float* __restrict__ x, const _Float16* __restrict__ Wt2,
    _Float16* __restrict__ Qh, _Float16* __restrict__ Kpk,
    _Float16* __restrict__ Vpk)
{
    __shared__ _Float16 xs[2][32][72];                // 9216 B
    const int tid  = threadIdx.x;
    const int lane = tid & 63, w = tid >> 6;
    const int q    = lane >> 4, c = lane & 15;
    const int nt   = w & 1;                           // n-half (16 rows)
    const int mg   = w >> 1;                          // m-group (3 m-tiles)
    const int row0 = blockIdx.x * 32;

    const int srow = tid >> 4, scol = (tid & 15) * 4;
    const float* xg = x + (size_t)(row0 + srow) * C_ + scol;

    floatx4 acc[3];
    #pragma unroll
    for (int i = 0; i < 3; ++i) acc[i] = floatx4{0.f, 0.f, 0.f, 0.f};

    float4 g = *(const float4*)xg;                    // preload tile 0

    for (int j = 0; j < 16; ++j) {
        half4_ hv;
        hv[0] = (_Float16)g.x; hv[1] = (_Float16)g.y;
        hv[2] = (_Float16)g.z; hv[3] = (_Float16)g.w;
        *(half4_*)(&xs[j & 1][srow][scol]) = hv;
        __syncthreads();
        if (j < 15) g = *(const float4*)(xg + (j + 1) * 64);

        const _Float16* xrow = &xs[j & 1][nt * 16 + c][q * 8];
        const half8 b0 = *(const half8*)xrow;
        const half8 b1 = *(const half8*)(xrow + 32);

        half8 a[6];
        #pragma unroll
        for (int i = 0; i < 3; ++i) {
            const size_t fb = ((size_t)((mg * 3 + i) * 16 + j) * 2) * 512 + lane * 8;
            a[i * 2]     = *(const half8*)(Wt2 + fb);
            a[i * 2 + 1] = *(const half8*)(Wt2 + fb + 512);
        }
        #pragma unroll
        for (int i = 0; i < 3; ++i) {
            acc[i] = MFMA16(a[i * 2],     b0, acc[i]);
            acc[i] = MFMA16(a[i * 2 + 1], b1, acc[i]);
        }
    }

    const int row = row0 + nt * 16 + c;
    const int b = row >> 12, t4 = row & (T_ - 1);
    const int kt = t4 >> 6;
    const size_t tbase = ((size_t)b * 64 + kt) * 4096;
    const int mtk = (t4 >> 4) & 3;
    const int kk  = t4 & 63;

    #pragma unroll
    for (int i = 0; i < 3; ++i) {
        const int gi = mg * 3 + i;
        if (gi < 4) {                                 // Q row-major
            half4_ v;
            #pragma unroll
            for (int r = 0; r < 4; ++r) v[r] = (_Float16)acc[i][r];
            *(half4_*)(Qh + (size_t)row * H_ + gi * 16 + q * 4) = v;
        } else if (gi < 8) {                          // K fragment-packed (16x16x32 A-frag)
            half4_ v;
            #pragma unroll
            for (int r = 0; r < 4; ++r) v[r] = (_Float16)acc[i][r];
            const int e  = gi - 4;
            const int f  = e >> 1;
            const int qa = (e * 2 + (q >> 1)) & 3;
            *(half4_*)(Kpk + tbase + ((size_t)(mtk * 2 + f) * 64 + qa * 16 + c) * 8
                       + (q & 1) * 4) = v;
        } else {                                      // V 16x16x16 A-frag packed
            const int mtv = gi - 8;
            const int qa2 = (kk >> 2) & 3;
            const int h4  = (kk >> 4) & 1;
            const int f2  = kk >> 5;
            const int i2  = kk & 3;
            #pragma unroll
            for (int r = 0; r < 4; ++r) {
                const int cv = q * 4 + r;             // h & 15
                Vpk[tbase + ((size_t)(mtv * 2 + f2) * 64 + qa2 * 16 + cv) * 8
                    + h4 * 4 + i2] = (_Float16)acc[i][r];
            }
        }
    }
}

// ---------------------------------------------------------------------------
// Kernel 3: causal flash attention — measured optimum (r13, 136.88 us total).
// QBLK=16, 1024 blocks x 512 thr (4 blk/CU, 16 waves/CU), 8-way in-block
// split-K, per-wave K/V register loads with guarded K(kt+8) prefetch,
// V-after-QK, P-in-register PV (16x16x16 MFMA), T13 defer-rescale, setprio,
// pure-LDS 8-wave combine, direct out.  The full traffic/register matrix
// was measured (r2-r14): every cheaper-traffic structure loses more in
// occupancy (QBLK=32: spill@128-reg or 12-wave cap) or plumbing (split-K
// partials/fences) than it saves.  ~33 us = 455 MB K/V @ ~13.8 TB/s L2/L3.
// ---------------------------------------------------------------------------
__global__ __launch_bounds__(512, 4) void attn_kn(
    const _Float16* __restrict__ Qh, const _Float16* __restrict__ Kpk,
    const _Float16* __restrict__ Vpk, float* __restrict__ out)
{
    __shared__ __align__(16) char smem[36864];
    const int lane = threadIdx.x & 63;
    const int w    = threadIdx.x >> 6;                // 0..7
    const int q    = lane >> 4, c = lane & 15;

    // XCD-aware decode: batch per XCD pair, heavy tiles first
    const int bid  = blockIdx.x;
    const int xcd  = bid & 7;
    const int slot = bid >> 3;                        // 0..127
    const int b    = xcd >> 1;
    const int t    = 255 - ((slot << 1) | (xcd & 1));
    const int row0 = t * 16;
    const int grow = b * T_ + row0;
    const int nk   = (t >> 2) + 1;                    // 64-key tiles (last=diag)

    // Q B-frag, pre-scaled by (1/8)*log2(e)
    half8 bq0 = *(const half8*)(Qh + (size_t)(grow + c) * H_ + q * 8);
    half8 bq1 = *(const half8*)(Qh + (size_t)(grow + c) * H_ + 32 + q * 8);
    const _Float16 qs = (_Float16)0.18033688f;
    bq0 *= qs; bq1 *= qs;

    floatx4 o[4];
    #pragma unroll
    for (int i = 0; i < 4; ++i) o[i] = floatx4{0.f, 0.f, 0.f, 0.f};
    float m = -3.0e38f, l = 0.f;

    const _Float16* Kb = Kpk + (size_t)b * 262144;    // b * 64 * 4096
    const _Float16* Vb = Vpk + (size_t)b * 262144;

    half8 k0[4], k1[4], v0[4], v1[4];
    {   // preload K for this wave's first tile (kt = w; always in-bounds)
        const _Float16* Kt = Kb + (size_t)w * 4096;
        #pragma unroll
        for (int mt = 0; mt < 4; ++mt) {
            k0[mt] = *(const half8*)(Kt + ((mt * 2)     * 64 + lane) * 8);
            k1[mt] = *(const half8*)(Kt + ((mt * 2 + 1) * 64 + lane) * 8);
        }
    }

    #pragma unroll 1
    for (int kt = w; kt < nk; kt += 8) {
        const int kb = kt * 64;

        // QK^T: 64 keys x 16 q
        floatx4 s[4];
        __builtin_amdgcn_s_setprio(1);
        #pragma unroll
        for (int mt = 0; mt < 4; ++mt) {
            floatx4 z = floatx4{0.f, 0.f, 0.f, 0.f};
            z = MFMA16(k0[mt], bq0, z);
            s[mt] = MFMA16(k1[mt], bq1, z);
        }
        __builtin_amdgcn_s_setprio(0);

        // V(kt): latency hides under softmax
        const _Float16* Vt = Vb + (size_t)kt * 4096;
        #pragma unroll
        for (int mt = 0; mt < 4; ++mt) {
            v0[mt] = *(const half8*)(Vt + ((mt * 2)     * 64 + lane) * 8);
            v1[mt] = *(const half8*)(Vt + ((mt * 2 + 1) * 64 + lane) * 8);
        }
        // K(kt+8) prefetch into the just-freed K regs (guarded, wave-uniform)
        if (kt + 8 < nk) {
            const _Float16* Kt = Kb + (size_t)(kt + 8) * 4096;
            #pragma unroll
            for (int mt = 0; mt < 4; ++mt) {
                k0[mt] = *(const half8*)(Kt + ((mt * 2)     * 64 + lane) * 8);
                k1[mt] = *(const half8*)(Kt + ((mt * 2 + 1) * 64 + lane) * 8);
            }
        }

        if (kt == nk - 1) {                           // causal mask (diag tile)
            #pragma unroll
            for (int mt = 0; mt < 4; ++mt)
                #pragma unroll
                for (int r = 0; r < 4; ++r)
                    if (kb + mt * 16 + q * 4 + r > row0 + c) s[mt][r] = -3.0e38f;
        }

        // online softmax, lane holds 16 scores of ONE q-row; defer-rescale
        float mx = s[0][0];
        #pragma unroll
        for (int mt = 0; mt < 4; ++mt)
            #pragma unroll
            for (int r = 0; r < 4; ++r) mx = fmaxf(mx, s[mt][r]);
        mx = fmaxf(mx, __shfl_xor(mx, 16, 64));
        mx = fmaxf(mx, __shfl_xor(mx, 32, 64));
        if (!__all(mx <= m + 8.f)) {                  // T13: rescale only on growth
            const float mn    = fmaxf(m, mx);
            const float alpha = exp2f(m - mn);
            l *= alpha;
            #pragma unroll
            for (int mt = 0; mt < 4; ++mt) o[mt] *= alpha;
            m = mn;
        }
        half4_ ph[4];
        float sl = 0.f;
        #pragma unroll
        for (int mt = 0; mt < 4; ++mt)
            #pragma unroll
            for (int r = 0; r < 4; ++r) {
                const float ev = exp2f(s[mt][r] - m);
                sl += ev;
                ph[mt][r] = (_Float16)ev;
            }
        sl += __shfl_xor(sl, 16, 64);
        sl += __shfl_xor(sl, 32, 64);
        l += sl;

        // O^T += V^T · P^T (P stays in registers as 16x16x16 B-frags)
        __builtin_amdgcn_s_setprio(1);
        #pragma unroll
        for (int mt = 0; mt < 4; ++mt) {
            o[mt] = MFMA16K(LO4(v0[mt]), ph[0], o[mt]);
            o[mt] = MFMA16K(HI4(v0[mt]), ph[1], o[mt]);
            o[mt] = MFMA16K(LO4(v1[mt]), ph[2], o[mt]);
            o[mt] = MFMA16K(HI4(v1[mt]), ph[3], o[mt]);
        }
        __builtin_amdgcn_s_setprio(0);
    }

    // ---- flash combine across the 8 waves (direct out write) -------------
    float* Ol = (float*)smem;                         // [8][1088] (pad 17)
    float* Ml = (float*)(smem + 34816);               // [8][16]
    float* Ll = (float*)(smem + 35328);               // [8][16]
    if (q == 0) Ml[w * 16 + c] = m;
    __syncthreads();
    float M = Ml[c];
    #pragma unroll
    for (int w2 = 1; w2 < 8; ++w2) M = fmaxf(M, Ml[w2 * 16 + c]);
    const float alpha = exp2f(m - M);                 // 0 for empty waves
    if (q == 0) Ll[w * 16 + c] = l * alpha;
    #pragma unroll
    for (int mt = 0; mt < 4; ++mt)
        #pragma unroll
        for (int r = 0; r < 4; ++r)
            Ol[w * 1088 + (mt * 16 + q * 4 + r) * 17 + c] = o[mt][r] * alpha;
    __syncthreads();

    float L = 0.f;
    #pragma unroll
    for (int w2 = 0; w2 < 8; ++w2) L += Ll[w2 * 16 + c];
    const float inv = 1.f / L;
    const int h0 = w * 8 + q * 2;
    float ox = 0.f, oy = 0.f;
    #pragma unroll
    for (int w2 = 0; w2 < 8; ++w2) {
        ox += Ol[w2 * 1088 + h0 * 17 + c];
        oy += Ol[w2 * 1088 + (h0 + 1) * 17 + c];
    }
    float2 st; st.x = ox * inv; st.y = oy * inv;
    *(float2*)(out + (size_t)(grow + c) * H_ + h0) = st;
}

extern "C" void kernel_launch(void* const* d_in, const int* in_sizes, int n_in,
                              void* d_out, int out_size, void* d_ws, size_t ws_size,
                              hipStream_t stream) {
    const float* x  = (const float*)d_in[0];
    const float* Wq = (const float*)d_in[1];
    const float* Wk = (const float*)d_in[2];
    const float* Wv = (const float*)d_in[3];
    float* out = (float*)d_out;

    _Float16* ws = (_Float16*)d_ws;
    _Float16* Wt2 = ws;                               //   192*1024 = 196608
    _Float16* Qh  = ws + 196608;                      // 16384*64  = 1048576
    _Float16* Kpk = Qh + 1048576;                     // [4][64][4096]
    _Float16* Vpk = Kpk + 1048576;                    // [4][64][4096]

    hipLaunchKernelGGL(pack_w_kn, dim3(96), dim3(256), 0, stream, Wq, Wk, Wv, Wt2);
    hipLaunchKernelGGL(qkv_kn, dim3((B_ * T_) / 32), dim3(512), 0, stream,
                       x, Wt2, Qh, Kpk, Vpk);
    hipLaunchKernelGGL(attn_kn, dim3(1024), dim3(512), 0, stream,
                       Qh, Kpk, Vpk, out);
}